// Round 3
// baseline (1019.630 us; speedup 1.0000x reference)
//
#include <hip/hip_runtime.h>
#include <hip/hip_bf16.h>

#define D_    4096
#define KVH_  8
#define HD_   128
#define MAXS_ 4096
#define M_    256
#define NCH   8                  // kv split chunks
#define TPC   (MAXS_ / NCH)      // 512 kv positions per chunk

using frag_ab = __attribute__((ext_vector_type(8))) short;   // 8 x bf16
using frag_cd = __attribute__((ext_vector_type(4))) float;   // 4 x f32

__device__ __forceinline__ short bfb(float f) {
  union { float f; unsigned u; } cv; cv.f = f;
  unsigned u = cv.u;
  return (short)((u + 0x7fffu + ((u >> 16) & 1u)) >> 16);  // RN-even fp32->bf16
}
__device__ __forceinline__ float b2f(short s) {
  union { float f; unsigned u; } cv; cv.u = ((unsigned)(unsigned short)s) << 16; return cv.f;
}
__device__ __forceinline__ short4 cvt4(float4 v) {
  short4 o; o.x = bfb(v.x); o.y = bfb(v.y); o.z = bfb(v.z); o.w = bfb(v.w); return o;
}
__device__ __forceinline__ float4 f4_of_s4(short4 s) {
  return make_float4(b2f(s.x), b2f(s.y), b2f(s.z), b2f(s.w));
}

// ---- async global->LDS, 16B per lane (CK-style addrspace casts) ----
typedef const unsigned int __attribute__((address_space(1)))* gas_t;
typedef unsigned int __attribute__((address_space(3)))* las_t;
__device__ __forceinline__ void gl_lds16(const void* g, void* l) {
  __builtin_amdgcn_global_load_lds((gas_t)(unsigned long long)g,
                                   (las_t)(unsigned)(unsigned long long)l, 16, 0, 0);
}

// ---------------- zero fill ----------------
__global__ __launch_bounds__(256) void zero_kernel(float4* __restrict__ p, int n4) {
  int i = blockIdx.x * 256 + threadIdx.x;
  int st = gridDim.x * 256;
  for (; i < n4; i += st) p[i] = make_float4(0.f, 0.f, 0.f, 0.f);
}

// ---------------- prep: weight transposes (f32 KxN -> bf16 NxK) + x -> bf16 ----------
// tiles (64x64): Wq 0..4095, Wk 4096..5119, Wv 5120..6143, Wo 6144..10239, x 10240..10255
__global__ __launch_bounds__(256) void prep_kernel(
    const float* __restrict__ Wq, const float* __restrict__ Wk,
    const float* __restrict__ Wv, const float* __restrict__ Wo,
    const float* __restrict__ x,
    short* __restrict__ Wqkv_t,   // [6144][4096]
    short* __restrict__ Wo_t,     // [4096][4096]
    short* __restrict__ x_bf)     // [256][4096]
{
  int idx = blockIdx.x;
  int tid = threadIdx.x;
  if (idx >= 10240) {
    int j0 = (idx - 10240) * 256 + tid;
    const float4* xs = (const float4*)x;
    for (int j = j0; j < (M_ * D_) / 4; j += 16 * 256) {
      *(short4*)(x_bf + (size_t)j * 4) = cvt4(xs[j]);
    }
    return;
  }
  const float* W; short* Wt; int N; int tile;
  if (idx < 4096)      { W = Wq; Wt = Wqkv_t;                          N = 4096; tile = idx; }
  else if (idx < 5120) { W = Wk; Wt = Wqkv_t + (size_t)4096 * 4096;    N = 1024; tile = idx - 4096; }
  else if (idx < 6144) { W = Wv; Wt = Wqkv_t + (size_t)5120 * 4096;    N = 1024; tile = idx - 5120; }
  else                 { W = Wo; Wt = Wo_t;                            N = 4096; tile = idx - 6144; }
  int ntn = N >> 6;
  int tk = tile / ntn, tn = tile - tk * ntn;
  int k0 = tk << 6, n0 = tn << 6;
  __shared__ __align__(16) short tb[64 * 72];   // [n][k], stride 72 (16B-aligned rows)
#pragma unroll
  for (int p = 0; p < 4; p++) {
    int seg = p * 256 + tid;
    int r = seg >> 4, c4 = (seg & 15) << 2;
    float4 v = *(const float4*)(W + (size_t)(k0 + r) * N + n0 + c4);
    tb[(c4 + 0) * 72 + r] = bfb(v.x);
    tb[(c4 + 1) * 72 + r] = bfb(v.y);
    tb[(c4 + 2) * 72 + r] = bfb(v.z);
    tb[(c4 + 3) * 72 + r] = bfb(v.w);
  }
  __syncthreads();
#pragma unroll
  for (int p = 0; p < 2; p++) {
    int seg = p * 256 + tid;
    int n = seg >> 3, k8 = (seg & 7) << 3;
    frag_ab v = *(const frag_ab*)(&tb[n * 72 + k8]);
    *(frag_ab*)(Wt + (size_t)(n0 + n) * 4096 + k0 + k8) = v;   // 16B store
  }
}

// ---------------- split-K GEMM: A bf16 [M][4096] x Bt bf16 [N][4096] -> atomic f32 ----
// grid (Nout/128, M/128, 8); each block does 128x128x512, atomicAdd into out.
__global__ __launch_bounds__(256, 3) void gemm_sk(
    const short* __restrict__ A, const short* __restrict__ Bt,
    float* __restrict__ out, int Nout)
{
  __shared__ __align__(16) short lds_a[128 * 64];
  __shared__ __align__(16) short lds_b[128 * 64];
  int tid = threadIdx.x;
  int wave = tid >> 6, lane = tid & 63, quad = lane >> 4, l16 = lane & 15;
  int n0 = blockIdx.x * 128, m0 = blockIdx.y * 128;
  int lrow = lane >> 3, lcol = lane & 7;
  int mq = (wave >> 1) * 64, nq = (wave & 1) * 64;

  const frag_cd fz = {0.f, 0.f, 0.f, 0.f};
  frag_cd acc[4][4];
#pragma unroll
  for (int i = 0; i < 4; i++)
#pragma unroll
    for (int j = 0; j < 4; j++) acc[i][j] = fz;

  int kbeg = blockIdx.z * 512;
  for (int kk = kbeg; kk < kbeg + 512; kk += 64) {
    __syncthreads();
#pragma unroll
    for (int i = 0; i < 4; i++) {
      int r = wave * 32 + i * 8;
      gl_lds16(A  + (size_t)(m0 + r + lrow) * 4096 + kk + lcol * 8, &lds_a[r * 64]);
      gl_lds16(Bt + (size_t)(n0 + r + lrow) * 4096 + kk + lcol * 8, &lds_b[r * 64]);
    }
    __syncthreads();
#pragma unroll
    for (int k0 = 0; k0 < 64; k0 += 32) {
      frag_ab af[4], bf[4];
#pragma unroll
      for (int i = 0; i < 4; i++) {
        af[i] = *(const frag_ab*)(&lds_a[(mq + i * 16 + l16) * 64 + k0 + quad * 8]);
        bf[i] = *(const frag_ab*)(&lds_b[(nq + i * 16 + l16) * 64 + k0 + quad * 8]);
      }
#pragma unroll
      for (int mi = 0; mi < 4; mi++)
#pragma unroll
        for (int ni = 0; ni < 4; ni++)
          acc[mi][ni] = __builtin_amdgcn_mfma_f32_16x16x32_bf16(af[mi], bf[ni], acc[mi][ni], 0, 0, 0);
    }
  }
#pragma unroll
  for (int mi = 0; mi < 4; mi++)
#pragma unroll
    for (int ni = 0; ni < 4; ni++)
#pragma unroll
      for (int r = 0; r < 4; r++) {
        int m = m0 + mq + mi * 16 + quad * 4 + r;
        int n = n0 + nq + ni * 16 + l16;
        atomicAdd(&out[(size_t)m * Nout + n], acc[mi][ni][r]);
      }
}

// ---------------- RoPE + convert qkv_acc f32 -> q/k/v bf16 ----------------
__global__ __launch_bounds__(256) void rope_convert(
    const float* __restrict__ qkv, short* __restrict__ q_bf,
    short* __restrict__ k_bf, short* __restrict__ v_bf, const int* __restrict__ sp)
{
  int start_pos = *sp;
  int i = blockIdx.x * 256 + threadIdx.x;       // float4 index, total 393216
  int m = i / 1536;
  int n = (i - m * 1536) * 4;
  float4 x = *(const float4*)(qkv + (size_t)m * 6144 + n);
  short4 o;
  if (n < 5120) {
    int pi = (n & 127) >> 1;
    float pos = (float)(start_pos + (m & 15));
    const float C = 0.2076205059304601f;        // log2(10000)/64
    float t0 = exp2f(-(float)pi * C);
    float t1 = exp2f(-(float)(pi + 1) * C);
    float s0, c0, s1, c1;
    sincosf(pos * t0, &s0, &c0);
    sincosf(pos * t1, &s1, &c1);
    o.x = bfb(x.x * c0 - x.y * s0); o.y = bfb(x.x * s0 + x.y * c0);
    o.z = bfb(x.z * c1 - x.w * s1); o.w = bfb(x.z * s1 + x.w * c1);
  } else {
    o = cvt4(x);
  }
  if (n < 4096)      *(short4*)(q_bf + (size_t)m * 4096 + n) = o;
  else if (n < 5120) *(short4*)(k_bf + (size_t)m * 1024 + (n - 4096)) = o;
  else               *(short4*)(v_bf + (size_t)m * 1024 + (n - 5120)) = o;
}

// ---------------- flash attention, split-kv, software-pipelined staging ----------------
#define KLD 136
#define VLD 72
#define PLD 72

__global__ __launch_bounds__(256, 3) void attn_kernel(
    const short* __restrict__ qb, const short* __restrict__ kb,
    const short* __restrict__ vb,
    const float* __restrict__ cache_k, const float* __restrict__ cache_v,
    float* __restrict__ part_ctx, float* __restrict__ part_m,
    float* __restrict__ part_l, const int* __restrict__ sp)
{
  __shared__ __align__(16) short k_s[64 * KLD];   // 17408 B
  __shared__ __align__(16) short vT[HD_ * VLD];   // 18432 B
  short* p_s = k_s;                               // aliased (barrier C guards)

  int chunk = blockIdx.x, kvh = blockIdx.y, b = blockIdx.z;
  int tid = threadIdx.x;
  int wave = tid >> 6, lane = tid & 63, quad = lane >> 4, l16 = lane & 15;
  int start_pos = *sp;
  int rloc = tid >> 5;
  int hd4 = (tid & 31) * 4;
  const float scale = 0.08838834764831845f;

  frag_ab qf[4];
  {
    const short* qrow = qb + (size_t)(b * 16 + l16) * D_ + (kvh * 4 + wave) * HD_;
#pragma unroll
    for (int k0 = 0; k0 < 4; k0++)
      qf[k0] = *(const frag_ab*)(qrow + k0 * 32 + quad * 8);
  }

  const frag_cd fz = {0.f, 0.f, 0.f, 0.f};
  frag_cd acc_o[8];
#pragma unroll
  for (int i = 0; i < 8; i++) acc_o[i] = fz;
  float m_i[4], l_i[4];
#pragma unroll
  for (int r = 0; r < 4; r++) { m_i[r] = -1e30f; l_i[r] = 0.f; }

  auto ld_pair = [&](int t, float4& kq, float4& vq) {
    if (t < start_pos) {
      size_t off = (((size_t)b * MAXS_ + t) * KVH_ + kvh) * HD_ + hd4;
      kq = *(const float4*)(cache_k + off);
      vq = *(const float4*)(cache_v + off);
    } else {
      int s = t - start_pos;
      size_t off = (size_t)(b * 16 + s) * (KVH_ * HD_) + kvh * HD_ + hd4;
      kq = f4_of_s4(*(const short4*)(kb + off));
      vq = f4_of_s4(*(const short4*)(vb + off));
    }
  };

  float4 kr[8], vr[8];
#pragma unroll
  for (int p = 0; p < 8; p++) ld_pair(chunk * TPC + p * 8 + rloc, kr[p], vr[p]);

  for (int it = 0; it < TPC / 64; it++) {
    short4 kc16[8], vc16[8];
#pragma unroll
    for (int p = 0; p < 8; p++) { kc16[p] = cvt4(kr[p]); vc16[p] = cvt4(vr[p]); }
    if (it + 1 < TPC / 64) {
      int tn = chunk * TPC + (it + 1) * 64;
#pragma unroll
      for (int p = 0; p < 8; p++) ld_pair(tn + p * 8 + rloc, kr[p], vr[p]);  // overlaps compute
    }
    __syncthreads();   // A: prior-iter LDS reads done
#pragma unroll
    for (int p = 0; p < 8; p++) {
      int row = p * 8 + rloc;
      *(short4*)(&k_s[row * KLD + hd4]) = kc16[p];
      int cb = row >> 3, wi = row & 7;
      vT[(hd4 + 0) * VLD + (((cb ^ (((hd4 + 0) >> 3) & 7)) << 3) | wi)] = vc16[p].x;
      vT[(hd4 + 1) * VLD + (((cb ^ (((hd4 + 1) >> 3) & 7)) << 3) | wi)] = vc16[p].y;
      vT[(hd4 + 2) * VLD + (((cb ^ (((hd4 + 2) >> 3) & 7)) << 3) | wi)] = vc16[p].z;
      vT[(hd4 + 3) * VLD + (((cb ^ (((hd4 + 3) >> 3) & 7)) << 3) | wi)] = vc16[p].w;
    }
    __syncthreads();   // B: tiles staged

    frag_cd sc[4];
#pragma unroll
    for (int i = 0; i < 4; i++) sc[i] = fz;
#pragma unroll
    for (int k0 = 0; k0 < HD_; k0 += 32) {
#pragma unroll
      for (int nt = 0; nt < 4; nt++) {
        frag_ab bfm = *(const frag_ab*)(&k_s[(nt * 16 + l16) * KLD + k0 + quad * 8]);
        sc[nt] = __builtin_amdgcn_mfma_f32_16x16x32_bf16(qf[k0 >> 5], bfm, sc[nt], 0, 0, 0);
      }
    }

    float alpha[4];
#pragma unroll
    for (int r = 0; r < 4; r++) {
      float mx = fmaxf(fmaxf(sc[0][r], sc[1][r]), fmaxf(sc[2][r], sc[3][r])) * scale;
#pragma unroll
      for (int off = 1; off < 16; off <<= 1) mx = fmaxf(mx, __shfl_xor(mx, off));
      float mnew = fmaxf(m_i[r], mx);
      alpha[r] = __expf(m_i[r] - mnew);
      m_i[r] = mnew;
      float rsum = 0.f;
#pragma unroll
      for (int nt = 0; nt < 4; nt++) {
        float p = __expf(sc[nt][r] * scale - mnew);
        sc[nt][r] = p;
        rsum += p;
      }
#pragma unroll
      for (int off = 1; off < 16; off <<= 1) rsum += __shfl_xor(rsum, off);
      l_i[r] = l_i[r] * alpha[r] + rsum;
    }
#pragma unroll
    for (int nt = 0; nt < 8; nt++)
#pragma unroll
      for (int r = 0; r < 4; r++) acc_o[nt][r] *= alpha[r];

    __syncthreads();   // C: k_s reads done before p_s overwrite
#pragma unroll
    for (int r = 0; r < 4; r++)
#pragma unroll
      for (int nt = 0; nt < 4; nt++)
        p_s[(wave * 16 + quad * 4 + r) * PLD + nt * 16 + l16] = bfb(sc[nt][r]);

#pragma unroll
    for (int k0 = 0; k0 < 64; k0 += 32) {
      frag_ab af = *(const frag_ab*)(&p_s[(wave * 16 + l16) * PLD + k0 + quad * 8]);
      int tbk = (k0 >> 3) + quad;
#pragma unroll
      for (int nt = 0; nt < 8; nt++) {
        int hd = nt * 16 + l16;
        frag_ab bfm = *(const frag_ab*)(&vT[hd * VLD + ((tbk ^ ((hd >> 3) & 7)) << 3)]);
        acc_o[nt] = __builtin_amdgcn_mfma_f32_16x16x32_bf16(af, bfm, acc_o[nt], 0, 0, 0);
      }
    }
  }

  int blk = ((b * 8 + kvh) << 3) + chunk;
#pragma unroll
  for (int nt = 0; nt < 8; nt++)
#pragma unroll
    for (int r = 0; r < 4; r++) {
      int qrow = wave * 16 + quad * 4 + r;
      part_ctx[((size_t)blk * 64 + qrow) * HD_ + nt * 16 + l16] = acc_o[nt][r];
    }
  if (l16 == 0) {
#pragma unroll
    for (int r = 0; r < 4; r++) {
      int qrow = wave * 16 + quad * 4 + r;
      part_m[blk * 64 + qrow] = m_i[r];
      part_l[blk * 64 + qrow] = l_i[r];
    }
  }
}

// ---------------- combine split-kv partials -> ctx bf16 ----------------
__global__ __launch_bounds__(256) void combine_kernel(
    const float* __restrict__ part_ctx, const float* __restrict__ part_m,
    const float* __restrict__ part_l, short* __restrict__ ctx_bf)
{
  int bk = blockIdx.x;            // b*8 + kvh
  int b = bk >> 3, kvh = bk & 7;
  int tid = threadIdx.x;
  __shared__ float w_s[8][64];
  __shared__ float inv_l[64];
  if (tid < 64) {
    float M = -1e30f;
#pragma unroll
    for (int c = 0; c < 8; c++) M = fmaxf(M, part_m[(bk * 8 + c) * 64 + tid]);
    float ls = 0.f;
#pragma unroll
    for (int c = 0; c < 8; c++) {
      float w = __expf(part_m[(bk * 8 + c) * 64 + tid] - M);
      w_s[c][tid] = w;
      ls += part_l[(bk * 8 + c) * 64 + tid] * w;
    }
    inv_l[tid] = 1.f / ls;
  }
  __syncthreads();
  for (int idx = tid; idx < 64 * 128; idx += 256) {
    int qrow = idx >> 7, hd = idx & 127;
    float acc = 0.f;
#pragma unroll
    for (int c = 0; c < 8; c++)
      acc += part_ctx[((size_t)(bk * 8 + c) * 64 + qrow) * HD_ + hd] * w_s[c][qrow];
    float val = acc * inv_l[qrow];
    int r = qrow >> 4, s = qrow & 15;
    ctx_bf[(size_t)(b * 16 + s) * D_ + (kvh * 4 + r) * HD_ + hd] = bfb(val);
  }
}

extern "C" void kernel_launch(void* const* d_in, const int* in_sizes, int n_in,
                              void* d_out, int out_size, void* d_ws, size_t ws_size,
                              hipStream_t stream)
{
  const float* x       = (const float*)d_in[0];
  const float* Wq      = (const float*)d_in[1];
  const float* Wk      = (const float*)d_in[2];
  const float* Wv      = (const float*)d_in[3];
  const float* Wo      = (const float*)d_in[4];
  const float* cache_k = (const float*)d_in[5];
  const float* cache_v = (const float*)d_in[6];
  const int*   sp      = (const int*)d_in[7];

  char* w = (char*)d_ws;
  auto alloc = [&](size_t bytes) { char* p = w; w += (bytes + 255) & ~(size_t)255; return p; };
  short* Wqkv_t  = (short*)alloc((size_t)6144 * 4096 * 2);
  short* Wo_t    = (short*)alloc((size_t)4096 * 4096 * 2);
  short* x_bf    = (short*)alloc((size_t)M_ * 4096 * 2);
  float* qkv_acc = (float*)alloc((size_t)M_ * 6144 * 4);
  short* q_bf    = (short*)alloc((size_t)M_ * 4096 * 2);
  short* k_bf    = (short*)alloc((size_t)M_ * 1024 * 2);
  short* v_bf    = (short*)alloc((size_t)M_ * 1024 * 2);
  short* ctx_bf  = (short*)alloc((size_t)M_ * 4096 * 2);
  float* part_ctx = (float*)alloc((size_t)1024 * 64 * 128 * 4);
  float* part_m   = (float*)alloc((size_t)1024 * 64 * 4);
  float* part_l   = (float*)alloc((size_t)1024 * 64 * 4);

  prep_kernel<<<10256, 256, 0, stream>>>(Wq, Wk, Wv, Wo, x, Wqkv_t, Wo_t, x_bf);
  zero_kernel<<<1536, 256, 0, stream>>>((float4*)qkv_acc, (M_ * 6144) / 4);
  zero_kernel<<<1024, 256, 0, stream>>>((float4*)d_out, (M_ * 4096) / 4);

  gemm_sk<<<dim3(48, 2, 8), 256, 0, stream>>>(x_bf, Wqkv_t, qkv_acc, 6144);
  rope_convert<<<1536, 256, 0, stream>>>(qkv_acc, q_bf, k_bf, v_bf, sp);

  attn_kernel<<<dim3(NCH, 8, 16), 256, 0, stream>>>(
      q_bf, k_bf, v_bf, cache_k, cache_v, part_ctx, part_m, part_l, sp);
  combine_kernel<<<128, 256, 0, stream>>>(part_ctx, part_m, part_l, ctx_bf);

  gemm_sk<<<dim3(32, 2, 8), 256, 0, stream>>>(ctx_bf, Wo_t, (float*)d_out, 4096);
}